// Round 6
// baseline (409.518 us; speedup 1.0000x reference)
//
#include <hip/hip_runtime.h>
#include <hip/hip_bf16.h>

#define Bc 4
#define Sc 2048
#define Dc 1024
#define Hc 16
#define DHc 64

typedef unsigned short u16;
typedef unsigned int u32;
typedef __attribute__((ext_vector_type(8))) short bfrag;
typedef __attribute__((ext_vector_type(4))) float f32x4;

#define SCALE_Q 0.18033688011112042f  /* 0.125 * log2(e): exp2-domain softmax */

// single-instruction hardware exp2 (v_exp_f32 computes 2^x).
__device__ __forceinline__ float exp2_hw(float x) {
  float r;
  asm("v_exp_f32 %0, %1" : "=v"(r) : "v"(x));
  return r;
}
#define EXP2(x) exp2_hw(x)

__device__ __forceinline__ u16 f2bf(float f) {
  u32 u = __float_as_uint(f);
  return (u16)((u + 0x7fffu + ((u >> 16) & 1u)) >> 16);
}
__device__ __forceinline__ float bf2f(u16 h) { return __uint_as_float(((u32)h) << 16); }

// packed f32x2 -> bf16x2: single v_cvt_pk_bf16_f32 (RNE).
__device__ __forceinline__ u32 pkbf(float a, float b) {
  u32 r;
  asm("v_cvt_pk_bf16_f32 %0, %1, %2" : "=v"(r) : "v"(a), "v"(b));
  return r;
}

union FB { bfrag f; u32 w[4]; };

// gfx950 fragment-redistribution swaps: both operands are read-write.
#if __has_builtin(__builtin_amdgcn_permlane32_swap) && __has_builtin(__builtin_amdgcn_permlane16_swap)
typedef __attribute__((ext_vector_type(2))) unsigned int u32x2;
__device__ __forceinline__ void pl32swap(u32& x, u32& y) {
  u32x2 r = __builtin_amdgcn_permlane32_swap(x, y, false, false);
  x = r.x; y = r.y;
}
__device__ __forceinline__ void pl16swap(u32& x, u32& y) {
  u32x2 r = __builtin_amdgcn_permlane16_swap(x, y, false, false);
  x = r.x; y = r.y;
}
#else
__device__ __forceinline__ void pl32swap(u32& x, u32& y) {
  asm volatile("v_permlane32_swap_b32 %0, %1" : "+v"(x), "+v"(y));
}
__device__ __forceinline__ void pl16swap(u32& x, u32& y) {
  asm volatile("v_permlane16_swap_b32 %0, %1" : "+v"(x), "+v"(y));
}
#endif

// async global->LDS, 16B per lane, dest = wave-uniform base + lane*16
__device__ __forceinline__ void gl_lds16(const u16* g, u16* l) {
  __builtin_amdgcn_global_load_lds(
      (const __attribute__((address_space(1))) unsigned int*)g,
      (__attribute__((address_space(3))) unsigned int*)l, 16, 0, 0);
}

// ---------------- prep: dtype detect, mask layout detect, mask bias, bias->f32 ----
__global__ __launch_bounds__(256) void prep_kernel(
    const void* __restrict__ qsrc, const void* __restrict__ mask,
    const void* __restrict__ bq, const void* __restrict__ bk,
    const void* __restrict__ bv, const void* __restrict__ bo,
    int* __restrict__ flags, float* __restrict__ maskf, float* __restrict__ biasf) {
  __shared__ int c_bf, c_ni, c_nf;
  const int tid = threadIdx.x;
  if (tid == 0) { c_bf = 0; c_ni = 0; c_nf = 0; }
  __syncthreads();
  u32 w = ((const u32*)qsrc)[tid];
  int e = (int)((w >> 7) & 0xffu);
  if (e >= 118 && e <= 130) atomicAdd(&c_bf, 1);
  int ni = 0, nf = 0;
  for (int i = tid; i < 2048; i += 256) {
    u32 v = ((const u32*)mask)[i];
    if (v > 1u) ni = 1;
    if (v != 0u && v != 0x3f800000u) nf = 1;
  }
  if (ni) atomicAdd(&c_ni, 1);
  if (nf) atomicAdd(&c_nf, 1);
  __syncthreads();
  const int isbf = (c_bf > 128) ? 1 : 0;
  const int layout = (c_ni == 0) ? 0 : ((c_nf == 0) ? 2 : 1); // 0=int32 1=byte 2=f32
  if (tid == 0) { flags[0] = isbf; flags[1] = layout; }
  for (int i = tid; i < Bc * Sc; i += 256) {
    int mv;
    if (layout == 0) mv = ((const int*)mask)[i];
    else if (layout == 1) mv = (int)((const unsigned char*)mask)[i];
    else mv = (((const u32*)mask)[i] != 0u) ? 1 : 0;
    maskf[i] = mv ? -1e30f : 0.0f;  // True = padding = excluded (exp2 -> 0)
  }
  const void* bs[4] = {bq, bk, bv, bo};
  for (int j = 0; j < 4; ++j) {
    const void* bp = bs[j];
    float sc = (j == 0) ? SCALE_Q : 1.0f;  // fold softmax scale into Q bias
    for (int i = tid; i < Dc; i += 256)
      biasf[j * Dc + i] = (isbf ? bf2f(((const u16*)bp)[i]) : ((const float*)bp)[i]) * sc;
  }
}

// ---------------- input -> bf16 convert (Q,K,V inputs), 8 elem/thread ------------
__global__ __launch_bounds__(256) void cvt3(
    const void* __restrict__ s0, const void* __restrict__ s1, const void* __restrict__ s2,
    u16* __restrict__ d0, u16* __restrict__ d1, u16* __restrict__ d2,
    const int* __restrict__ flags) {
  const void* s = blockIdx.y == 0 ? s0 : (blockIdx.y == 1 ? s1 : s2);
  u16* d = blockIdx.y == 0 ? d0 : (blockIdx.y == 1 ? d1 : d2);
  size_t e = ((size_t)blockIdx.x * 256 + threadIdx.x) * 8;
  if (flags[0]) {
    *(uint4*)(d + e) = *(const uint4*)((const u16*)s + e);
  } else {
    const float* p = (const float*)s + e;
    float4 f0 = *(const float4*)p, f1 = *(const float4*)(p + 4);
    uint4 st;
    st.x = pkbf(f0.x, f0.y); st.y = pkbf(f0.z, f0.w);
    st.z = pkbf(f1.x, f1.y); st.w = pkbf(f1.z, f1.w);
    *(uint4*)(d + e) = st;
  }
}

// ---------------- weight transposes (K x N -> N x K), all 4 in one launch --------
__global__ __launch_bounds__(256) void transpose_all(
    const void* __restrict__ W0, const void* __restrict__ W1,
    const void* __restrict__ W2, const void* __restrict__ W3,
    u16* __restrict__ D0, u16* __restrict__ D1, u16* __restrict__ D2,
    u16* __restrict__ D3, const int* __restrict__ flags) {
  __shared__ short ts[64][72];
  const int z = blockIdx.z;
  const void* W = z == 0 ? W0 : (z == 1 ? W1 : (z == 2 ? W2 : W3));
  u16* Wt = z == 0 ? D0 : (z == 1 ? D1 : (z == 2 ? D2 : D3));
  const float scale = (z == 0) ? SCALE_Q : 1.0f;
  const int r0 = blockIdx.y * 64, c0 = blockIdx.x * 64;
  const int isbf = flags[0];
  for (int i = 0; i < 2; ++i) {
    int ch = threadIdx.x + i * 256;
    int r = ch >> 3, c = (ch & 7) * 8;
    bfrag pk;
    if (isbf) {
      uint4 v = *(const uint4*)((const u16*)W + (size_t)(r0 + r) * Dc + c0 + c);
      const u16* pv = (const u16*)&v;
      for (int j = 0; j < 8; ++j) pk[j] = (short)f2bf(bf2f(pv[j]) * scale);
    } else {
      const float* p = (const float*)W + (size_t)(r0 + r) * Dc + c0 + c;
      float4 f0 = *(const float4*)p, f1 = *(const float4*)(p + 4);
      pk[0] = (short)f2bf(f0.x * scale); pk[1] = (short)f2bf(f0.y * scale);
      pk[2] = (short)f2bf(f0.z * scale); pk[3] = (short)f2bf(f0.w * scale);
      pk[4] = (short)f2bf(f1.x * scale); pk[5] = (short)f2bf(f1.y * scale);
      pk[6] = (short)f2bf(f1.z * scale); pk[7] = (short)f2bf(f1.w * scale);
    }
    *(bfrag*)(&ts[r][c]) = pk;
  }
  __syncthreads();
  for (int i = 0; i < 2; ++i) {
    int ch = threadIdx.x + i * 256;
    int n = ch >> 3, k = (ch & 7) * 8;
    u16 tmp[8] __attribute__((aligned(16)));
    for (int j = 0; j < 8; ++j) tmp[j] = (u16)ts[k + j][n];
    *(uint4*)(Wt + (size_t)(c0 + n) * Dc + r0 + k) = *(const uint4*)tmp;
  }
}

// ---------------- GEMM: C(MxN) = A(MxK) @ Bt(NxK)^T + bias ----------------------
// One-barrier async dbuf K-loop; optional z-fused triple launch (QKV).
#define BM 128
#define BN 128
#define BK 32

#define GEMM_STAGE(bufI)                                                          \
  {                                                                               \
    gl_lds16(bgp0, &Bs[bufI][wave * 16][0]);                                      \
    gl_lds16(bgp1, &Bs[bufI][wave * 16 + 64][0]);                                 \
    bgp0 += BK; bgp1 += BK;                                                       \
    if (a_bf) {                                                                   \
      gl_lds16(agp0, &As[bufI][wave * 16][0]);                                    \
      gl_lds16(agp1, &As[bufI][wave * 16 + 64][0]);                               \
      agp0 += BK; agp1 += BK;                                                     \
    } else {                                                                      \
      for (int i_ = 0; i_ < 2; ++i_) {                                            \
        int ch_ = tid + i_ * 256;                                                 \
        int r_ = ch_ >> 2, kc_ = (ch_ & 3) * 8;                                   \
        const float* p_ = (const float*)Araw + (size_t)(bm0 + r_) * K + ksf + kc_;\
        float4 f0_ = *(const float4*)p_, f1_ = *(const float4*)(p_ + 4);          \
        uint4 st_;                                                                \
        st_.x = pkbf(f0_.x, f0_.y); st_.y = pkbf(f0_.z, f0_.w);                   \
        st_.z = pkbf(f1_.x, f1_.y); st_.w = pkbf(f1_.z, f1_.w);                   \
        *(uint4*)(&As[bufI][r_][kc_]) = st_;                                      \
      }                                                                           \
    }                                                                             \
    ksf += BK;                                                                    \
  }

__global__ __launch_bounds__(256) void gemm_bt(
    const void* __restrict__ Araw, const u16* __restrict__ Bt,
    const float* __restrict__ bias, void* __restrict__ Cout, u16* __restrict__ VtOut,
    const int* __restrict__ flags, int M, int N, int K,
    int a_mode /*1=A always bf16*/, int c_mode /*0=bf16 1=per-flags 2=V^T*/,
    int qkv /*1 = triple launch via blockIdx.z*/) {
  __shared__ __align__(16) u16 As[2][BM][BK];  // 2 x 8 KB
  __shared__ __align__(16) u16 Bs[2][BN][BK];
  if (qkv) {
    const int z = blockIdx.z;
    Araw = (const void*)((const u16*)Araw + (size_t)z * Bc * Sc * Dc);
    Bt += (size_t)z * Dc * Dc;
    bias += z * Dc;
    if (z == 2) { c_mode = 2; Cout = (void*)VtOut; }
    else Cout = (void*)((u16*)Cout + (size_t)z * Bc * Sc * Dc);
  }
  const int tid = threadIdx.x;
  const int lane = tid & 63, wave = tid >> 6;
  const int lr = lane & 15, lq = lane >> 4;
  const int ntiles = N >> 7;
  const int band = (M >> 7) >> 3;
  const int L = blockIdx.x;
  const int mt = (L & 7) * band + ((L >> 3) / ntiles);
  const int nt = (L >> 3) % ntiles;
  const int bm0 = mt * BM, bn0 = nt * BN;
  const int wm = (wave >> 1) * 64, wn = (wave & 1) * 64;
  const int a_bf = a_mode ? 1 : flags[0];
  const int srow = lane >> 2;
  const int schunk = lane & 3;
  const u16* bgp0 = Bt + (size_t)(bn0 + wave * 16 + srow) * K + schunk * 8;
  const u16* bgp1 = bgp0 + (size_t)64 * K;
  const u16* agp0 = (const u16*)Araw + (size_t)(bm0 + wave * 16 + srow) * K + schunk * 8;
  const u16* agp1 = agp0 + (size_t)64 * K;
  int ksf = 0;
  f32x4 acc[4][4] = {};
  GEMM_STAGE(0);
  __syncthreads();
  const int NIT = K / BK;
#pragma unroll 2
  for (int it = 0; it < NIT; ++it) {
    const int p = it & 1;
    if (it + 1 < NIT) { GEMM_STAGE(p ^ 1); }
    bfrag af[4], bf[4];
    for (int mi = 0; mi < 4; ++mi) af[mi] = *(const bfrag*)(&As[p][wm + mi * 16 + lr][lq * 8]);
    for (int nj = 0; nj < 4; ++nj) bf[nj] = *(const bfrag*)(&Bs[p][wn + nj * 16 + lr][lq * 8]);
    for (int mi = 0; mi < 4; ++mi)
      for (int nj = 0; nj < 4; ++nj)
        acc[mi][nj] = __builtin_amdgcn_mfma_f32_16x16x32_bf16(af[mi], bf[nj], acc[mi][nj], 0, 0, 0);
    __syncthreads();
  }
  float bcol[4];
  for (int nj = 0; nj < 4; ++nj) bcol[nj] = bias[bn0 + wn + nj * 16 + lr];
  if (c_mode == 2) {
    // write V^T: dst[((b*H+h)*64 + d)][s], 4 consecutive s per lane = 8B store
    u16* VT = (u16*)Cout;
    for (int mi = 0; mi < 4; ++mi)
      for (int nj = 0; nj < 4; ++nj) {
        int row = bm0 + wm + mi * 16 + lq * 4;       // s base (4 consecutive)
        int col = bn0 + wn + nj * 16 + lr;           // h*64+d
        float v0 = acc[mi][nj][0] + bcol[nj], v1 = acc[mi][nj][1] + bcol[nj];
        float v2 = acc[mi][nj][2] + bcol[nj], v3 = acc[mi][nj][3] + bcol[nj];
        uint2 st;
        st.x = pkbf(v0, v1);
        st.y = pkbf(v2, v3);
        size_t drow = (size_t)((row >> 11) * Hc + (col >> 6)) * DHc + (col & 63);
        *(uint2*)(VT + drow * Sc + (row & (Sc - 1))) = st;
      }
  } else {
    const int outbf = (c_mode == 0) ? 1 : flags[0];
    for (int mi = 0; mi < 4; ++mi)
      for (int r = 0; r < 4; ++r) {
        int row = bm0 + wm + mi * 16 + lq * 4 + r;
        for (int nj = 0; nj < 4; ++nj) {
          int col = bn0 + wn + nj * 16 + lr;
          float v = acc[mi][nj][r] + bcol[nj];
          if (outbf) ((u16*)Cout)[(size_t)row * N + col] = f2bf(v);
          else ((float*)Cout)[(size_t)row * N + col] = v;
        }
      }
  }
}

// ---------------- flash attention: QBLK=64 per wave, amortized K/V reads ---------
// S^T = K·Q^T + maskbias (LDS maskL as direct MFMA C-in); p = exp2(s) via
// v_exp_f32; pack via v_cvt_pk_bf16_f32; PV + rowsum at K=32 via permlane
// fragment redistribution. Each wave owns 64 q-rows (mi=0..3): K fragments
// amortize over 4 mi (8 ds_read -> 32 S-MFMA), V fragments over 4 mi
// (8 ds_read -> 32 PV-MFMA); barriers/staging/addressing per element halve.
// Grid 512 blocks -> 2 blocks/CU; co-resident blocks are barrier-independent,
// giving cross-block MFMA/VALU phase diversity.
__global__ __launch_bounds__(256) void attn_kernel(
    const u16* __restrict__ Q, const u16* __restrict__ K,
    const u16* __restrict__ Vt, const float* __restrict__ maskf,
    u16* __restrict__ Aout) {
  __shared__ __align__(16) u16 Ks[2][64][64];   // 2 x 8 KB, chunk^(row&7) swizzle
  __shared__ __align__(16) u16 Vts[2][64][64];  // 2 x 8 KB
  __shared__ float maskL[Sc];                   // 8 KB
  const int tid = threadIdx.x;
  const int lane = tid & 63, wave = tid >> 6;
  const int lr = lane & 15, lq = lane >> 4;
  const int bh = blockIdx.x;                    // all q-tiles of (b,h) -> same XCD
  const int b = bh >> 4, h = bh & 15;
  const int q0 = blockIdx.y * 256;
  const int wq = wave * 64;
  const int rr0 = wave * 16 + (lane >> 3);
  const int rr1 = rr0 + 8;
  const int cc = lane & 7;
  const u16* kg0 = K + (size_t)(b * Sc + rr0) * Dc + h * DHc + ((cc ^ (rr0 & 7)) * 8);
  const u16* kg1 = K + (size_t)(b * Sc + rr1) * Dc + h * DHc + ((cc ^ (rr1 & 7)) * 8);
  const u16* vg0 = Vt + (size_t)((b * Hc + h) * DHc + rr0) * Sc + ((cc ^ (rr0 & 7)) * 8);
  const u16* vg1 = Vt + (size_t)((b * Hc + h) * DHc + rr1) * Sc + ((cc ^ (rr1 & 7)) * 8);
#define STAGE_KV(bufI)                                        \
  {                                                           \
    gl_lds16(kg0, &Ks[bufI][wave * 16][0]);                   \
    gl_lds16(kg1, &Ks[bufI][wave * 16 + 8][0]);               \
    gl_lds16(vg0, &Vts[bufI][wave * 16][0]);                  \
    gl_lds16(vg1, &Vts[bufI][wave * 16 + 8][0]);              \
    kg0 += (size_t)64 * Dc; kg1 += (size_t)64 * Dc;           \
    vg0 += 64; vg1 += 64;                                     \
  }
  bfrag qf[4][2];
#pragma unroll
  for (int mi = 0; mi < 4; ++mi)
#pragma unroll
    for (int ks = 0; ks < 2; ++ks)
      qf[mi][ks] = *(const bfrag*)(Q + (size_t)(b * Sc + q0 + wq + mi * 16 + lr) * Dc +
                                   h * DHc + ks * 32 + lq * 8);
  f32x4 oacc[4][4] = {};  // O^T
  f32x4 oext[4] = {};     // row-sum accumulator (every reg = rsum(q=lr))
  FB ones;
  ones.w[0] = 0x3F803F80u; ones.w[1] = 0x3F803F80u; ones.w[2] = 0x3F803F80u; ones.w[3] = 0x3F803F80u;
  const int lrx = lr & 7;
  const int NT = Sc / 64;

  // ---- prologue: stage K0,V0; fill maskL; barrier ----
  STAGE_KV(0);
  {
    const float4* ms = (const float4*)(maskf + b * Sc);
    for (int i = tid; i < Sc / 4; i += 256) ((float4*)maskL)[i] = ms[i];
  }
  __syncthreads();

  for (int kt = 0; kt < NT; ++kt) {
    const int p = kt & 1;
    if (kt + 1 < NT) { STAGE_KV(p ^ 1); }
    // ---- S^T: C-in = mask bias (per-k, shared across mi); K frags reused 4x ----
    f32x4 sacc[4][4];
#pragma unroll
    for (int nk = 0; nk < 4; ++nk) {
      const int kr = nk * 16 + lr;
      const bfrag kf0 = *(const bfrag*)(&Ks[p][kr][(lq ^ lrx) * 8]);
      const bfrag kf1 = *(const bfrag*)(&Ks[p][kr][((4 + lq) ^ lrx) * 8]);
      const f32x4 mk = *(const f32x4*)(&maskL[kt * 64 + nk * 16 + lq * 4]);
#pragma unroll
      for (int mi = 0; mi < 4; ++mi) {
        f32x4 t = __builtin_amdgcn_mfma_f32_16x16x32_bf16(kf0, qf[mi][0], mk, 0, 0, 0);
        sacc[mi][nk] = __builtin_amdgcn_mfma_f32_16x16x32_bf16(kf1, qf[mi][1], t, 0, 0, 0);
      }
    }
    // ---- softmax + PV + rowsum; V frags reused 4x ----
#pragma unroll
    for (int c = 0; c < 2; ++c) {
      FB pb[4];
#pragma unroll
      for (int mi = 0; mi < 4; ++mi) {
        const f32x4 s0 = sacc[mi][2 * c];      // k = 32c + lq*4 + r
        const f32x4 s1 = sacc[mi][2 * c + 1];  // k = 32c + 16 + lq*4 + r
        u32 w0 = pkbf(EXP2(s0[0]), EXP2(s0[1]));
        u32 w1 = pkbf(EXP2(s0[2]), EXP2(s0[3]));
        u32 w2 = pkbf(EXP2(s1[0]), EXP2(s1[1]));
        u32 w3 = pkbf(EXP2(s1[2]), EXP2(s1[3]));
        pl32swap(w0, w2); pl16swap(w0, w2);
        pl32swap(w1, w3); pl16swap(w1, w3);
        pb[mi].w[0] = w0; pb[mi].w[1] = w1; pb[mi].w[2] = w2; pb[mi].w[3] = w3;
      }
#pragma unroll
      for (int nd = 0; nd < 4; ++nd) {
        const int dr = nd * 16 + lr;
        const bfrag vb = *(const bfrag*)(&Vts[p][dr][((4 * c + lq) ^ lrx) * 8]);
#pragma unroll
        for (int mi = 0; mi < 4; ++mi)
          oacc[mi][nd] = __builtin_amdgcn_mfma_f32_16x16x32_bf16(vb, pb[mi].f, oacc[mi][nd], 0, 0, 0);
      }
#pragma unroll
      for (int mi = 0; mi < 4; ++mi)
        oext[mi] = __builtin_amdgcn_mfma_f32_16x16x32_bf16(ones.f, pb[mi].f, oext[mi], 0, 0, 0);
    }
    __syncthreads();   // drains this iter's prefetch; protects buf p from overwrite
  }

#pragma unroll
  for (int mi = 0; mi < 4; ++mi) {
    float inv = 1.0f / oext[mi][0];
    u16* rowp = Aout + (size_t)(b * Sc + q0 + wq + mi * 16 + lr) * Dc + h * DHc;
#pragma unroll
    for (int nd = 0; nd < 4; ++nd) {
      float o0 = oacc[mi][nd][0] * inv, o1 = oacc[mi][nd][1] * inv;
      float o2 = oacc[mi][nd][2] * inv, o3 = oacc[mi][nd][3] * inv;
      uint2 st;
      st.x = pkbf(o0, o1);
      st.y = pkbf(o2, o3);
      *(uint2*)(rowp + nd * 16 + lq * 4) = st;
    }
  }
#undef STAGE_KV
}

extern "C" void kernel_launch(void* const* d_in, const int* in_sizes, int n_in,
                              void* d_out, int out_size, void* d_ws, size_t ws_size,
                              hipStream_t stream) {
  (void)in_sizes; (void)n_in; (void)out_size;
  char* ws = (char*)d_ws;
  int* flags = (int*)ws;                              // 256 B
  float* maskf = (float*)(ws + 256);                  // 32 KB
  float* biasf = (float*)(ws + 256 + Bc * Sc * 4);    // 16 KB
  u16* WqT = (u16*)(ws + 65536);
  u16* WkT = WqT + (size_t)Dc * Dc;
  u16* WvT = WkT + (size_t)Dc * Dc;
  u16* WoT = WvT + (size_t)Dc * Dc;
  u16* Qb  = WoT + (size_t)Dc * Dc;
  u16* Kb  = Qb + (size_t)Bc * Sc * Dc;
  u16* Vb  = Kb + (size_t)Bc * Sc * Dc;               // unused (V^T written directly)
  u16* Vtb = Vb + (size_t)Bc * Sc * Dc;
  u16* Ab  = Vtb + (size_t)Bc * Sc * Dc;
  u16* qbf = Ab + (size_t)Bc * Sc * Dc;               // bf16 copies of inputs (contiguous q,k,v)
  u16* kbf = qbf + (size_t)Bc * Sc * Dc;
  u16* vbf = kbf + (size_t)Bc * Sc * Dc;
  const size_t need = (size_t)((char*)(vbf + (size_t)Bc * Sc * Dc) - ws);
  const bool have_cvt = ws_size >= need;

  prep_kernel<<<1, 256, 0, stream>>>(d_in[0], d_in[3], d_in[5], d_in[7], d_in[9], d_in[11],
                                     flags, maskf, biasf);
  transpose_all<<<dim3(16, 16, 4), 256, 0, stream>>>(d_in[4], d_in[6], d_in[8], d_in[10],
                                                     WqT, WkT, WvT, WoT, flags);
  const int nblk = (Bc * Sc / BM) * (Dc / BN);        // 512
  if (have_cvt) {
    cvt3<<<dim3(4096, 3), 256, 0, stream>>>(d_in[0], d_in[1], d_in[2], qbf, kbf, vbf, flags);
    // z-fused QKV: z=0 -> Qb, z=1 -> Kb, z=2 -> V^T into Vtb (5 blocks/CU co-resident)
    gemm_bt<<<dim3(nblk, 1, 3), 256, 0, stream>>>(qbf, WqT, biasf, Qb, Vtb, flags,
                                                  Bc * Sc, Dc, Dc, 1, 0, 1);
  } else {
    gemm_bt<<<nblk, 256, 0, stream>>>(d_in[0], WqT, biasf, Qb, nullptr, flags,
                                      Bc * Sc, Dc, Dc, 0, 0, 0);
    gemm_bt<<<nblk, 256, 0, stream>>>(d_in[1], WkT, biasf + Dc, Kb, nullptr, flags,
                                      Bc * Sc, Dc, Dc, 0, 0, 0);
    gemm_bt<<<nblk, 256, 0, stream>>>(d_in[2], WvT, biasf + 2 * Dc, Vtb, nullptr, flags,
                                      Bc * Sc, Dc, Dc, 0, 2, 0);
  }
  attn_kernel<<<dim3(64, 8), 256, 0, stream>>>(Qb, Kb, Vtb, maskf, Ab);
  gemm_bt<<<nblk, 256, 0, stream>>>(Ab, WoT, biasf + 3 * Dc, d_out, nullptr, flags,
                                    Bc * Sc, Dc, Dc, 1, 1, 0);
}

// Round 7
// 348.646 us; speedup vs baseline: 1.1746x; 1.1746x over previous
//
#include <hip/hip_runtime.h>
#include <hip/hip_bf16.h>

#define Bc 4
#define Sc 2048
#define Dc 1024
#define Hc 16
#define DHc 64

typedef unsigned short u16;
typedef unsigned int u32;
typedef __attribute__((ext_vector_type(8))) short bfrag;
typedef __attribute__((ext_vector_type(4))) float f32x4;

#define SCALE_Q 0.18033688011112042f  /* 0.125 * log2(e): exp2-domain softmax */

// single-instruction hardware exp2 (v_exp_f32 computes 2^x).
__device__ __forceinline__ float exp2_hw(float x) {
  float r;
  asm("v_exp_f32 %0, %1" : "=v"(r) : "v"(x));
  return r;
}
#define EXP2(x) exp2_hw(x)

__device__ __forceinline__ u16 f2bf(float f) {
  u32 u = __float_as_uint(f);
  return (u16)((u + 0x7fffu + ((u >> 16) & 1u)) >> 16);
}
__device__ __forceinline__ float bf2f(u16 h) { return __uint_as_float(((u32)h) << 16); }

// packed f32x2 -> bf16x2: single v_cvt_pk_bf16_f32 (RNE).
__device__ __forceinline__ u32 pkbf(float a, float b) {
  u32 r;
  asm("v_cvt_pk_bf16_f32 %0, %1, %2" : "=v"(r) : "v"(a), "v"(b));
  return r;
}

union FB { bfrag f; u32 w[4]; };

// gfx950 fragment-redistribution swaps: both operands are read-write.
#if __has_builtin(__builtin_amdgcn_permlane32_swap) && __has_builtin(__builtin_amdgcn_permlane16_swap)
typedef __attribute__((ext_vector_type(2))) unsigned int u32x2;
__device__ __forceinline__ void pl32swap(u32& x, u32& y) {
  u32x2 r = __builtin_amdgcn_permlane32_swap(x, y, false, false);
  x = r.x; y = r.y;
}
__device__ __forceinline__ void pl16swap(u32& x, u32& y) {
  u32x2 r = __builtin_amdgcn_permlane16_swap(x, y, false, false);
  x = r.x; y = r.y;
}
#else
__device__ __forceinline__ void pl32swap(u32& x, u32& y) {
  asm volatile("v_permlane32_swap_b32 %0, %1" : "+v"(x), "+v"(y));
}
__device__ __forceinline__ void pl16swap(u32& x, u32& y) {
  asm volatile("v_permlane16_swap_b32 %0, %1" : "+v"(x), "+v"(y));
}
#endif

// async global->LDS, 16B per lane, dest = wave-uniform base + lane*16
__device__ __forceinline__ void gl_lds16(const u16* g, u16* l) {
  __builtin_amdgcn_global_load_lds(
      (const __attribute__((address_space(1))) unsigned int*)g,
      (__attribute__((address_space(3))) unsigned int*)l, 16, 0, 0);
}

// ---------------- flags only: dtype + mask layout detect (1 tiny block) ----------
__global__ __launch_bounds__(256) void prep_flags_k(
    const void* __restrict__ qsrc, const void* __restrict__ mask,
    int* __restrict__ flags) {
  __shared__ int c_bf, c_ni, c_nf;
  const int tid = threadIdx.x;
  if (tid == 0) { c_bf = 0; c_ni = 0; c_nf = 0; }
  __syncthreads();
  u32 w = ((const u32*)qsrc)[tid];
  int e = (int)((w >> 7) & 0xffu);
  if (e >= 118 && e <= 130) atomicAdd(&c_bf, 1);
  int ni = 0, nf = 0;
  for (int i = tid; i < 2048; i += 256) {
    u32 v = ((const u32*)mask)[i];
    if (v > 1u) ni = 1;
    if (v != 0u && v != 0x3f800000u) nf = 1;
  }
  if (ni) atomicAdd(&c_ni, 1);
  if (nf) atomicAdd(&c_nf, 1);
  __syncthreads();
  if (tid == 0) {
    flags[0] = (c_bf > 128) ? 1 : 0;
    flags[1] = (c_ni == 0) ? 0 : ((c_nf == 0) ? 2 : 1); // 0=int32 1=byte 2=f32
  }
}

// ---------------- fused aux: prep-fill + input cvt + weight transposes -----------
// One launch, role by blockIdx range (each block uniform-role; in-role barrier ok):
//   [0, 48)                 prep-fill: maskf (8192) + biasf (4096), 256 elem/blk
//   [48, 48+cvtBlocks)      cvt3: f32->bf16 (or copy) of q,k,v
//   [48+cvtBlocks, +1024)   transpose_all: 4 weights, 64x64 tiles
__global__ __launch_bounds__(256) void aux_all(
    const void* __restrict__ W0, const void* __restrict__ W1,
    const void* __restrict__ W2, const void* __restrict__ W3,
    u16* __restrict__ D0, u16* __restrict__ D1, u16* __restrict__ D2,
    u16* __restrict__ D3,
    const void* __restrict__ s0, const void* __restrict__ s1,
    const void* __restrict__ s2,
    u16* __restrict__ d0, u16* __restrict__ d1, u16* __restrict__ d2,
    const void* __restrict__ mask,
    const void* __restrict__ bq, const void* __restrict__ bk,
    const void* __restrict__ bv, const void* __restrict__ bo,
    const int* __restrict__ flags, float* __restrict__ maskf,
    float* __restrict__ biasf, int cvtBlocks) {
  __shared__ short ts[64][72];
  const int tid = threadIdx.x;
  const int bb = blockIdx.x;
  const int isbf = flags[0];
  if (bb < 48) {
    // ---- prep-fill ----
    int i = bb * 256 + tid;
    if (i < Bc * Sc) {
      const int layout = flags[1];
      int mv;
      if (layout == 0) mv = ((const int*)mask)[i];
      else if (layout == 1) mv = (int)((const unsigned char*)mask)[i];
      else mv = (((const u32*)mask)[i] != 0u) ? 1 : 0;
      maskf[i] = mv ? -1e30f : 0.0f;  // True = padding = excluded (exp2 -> 0)
    } else {
      int j = i - Bc * Sc;            // 0..4095
      int wsel = j >> 10, o = j & 1023;
      const void* bp = wsel == 0 ? bq : (wsel == 1 ? bk : (wsel == 2 ? bv : bo));
      float sc = (wsel == 0) ? SCALE_Q : 1.0f;  // fold softmax scale into Q bias
      biasf[j] = (isbf ? bf2f(((const u16*)bp)[o]) : ((const float*)bp)[o]) * sc;
    }
    return;
  }
  if (bb < 48 + cvtBlocks) {
    // ---- cvt3 ----
    int idx = bb - 48;
    int zy = idx >> 12, x = idx & 4095;         // cvtBlocks = 3*4096
    const void* s = zy == 0 ? s0 : (zy == 1 ? s1 : s2);
    u16* d = zy == 0 ? d0 : (zy == 1 ? d1 : d2);
    size_t e = ((size_t)x * 256 + tid) * 8;
    if (isbf) {
      *(uint4*)(d + e) = *(const uint4*)((const u16*)s + e);
    } else {
      const float* p = (const float*)s + e;
      float4 f0 = *(const float4*)p, f1 = *(const float4*)(p + 4);
      uint4 st;
      st.x = pkbf(f0.x, f0.y); st.y = pkbf(f0.z, f0.w);
      st.z = pkbf(f1.x, f1.y); st.w = pkbf(f1.z, f1.w);
      *(uint4*)(d + e) = st;
    }
    return;
  }
  // ---- weight transpose ----
  const int t = bb - (48 + cvtBlocks);
  const int z = t >> 8;
  const void* W = z == 0 ? W0 : (z == 1 ? W1 : (z == 2 ? W2 : W3));
  u16* Wt = z == 0 ? D0 : (z == 1 ? D1 : (z == 2 ? D2 : D3));
  const float scale = (z == 0) ? SCALE_Q : 1.0f;
  const int r0 = ((t >> 4) & 15) * 64, c0 = (t & 15) * 64;
  for (int i = 0; i < 2; ++i) {
    int ch = tid + i * 256;
    int r = ch >> 3, c = (ch & 7) * 8;
    bfrag pk;
    if (isbf) {
      uint4 v = *(const uint4*)((const u16*)W + (size_t)(r0 + r) * Dc + c0 + c);
      const u16* pv = (const u16*)&v;
      for (int j = 0; j < 8; ++j) pk[j] = (short)f2bf(bf2f(pv[j]) * scale);
    } else {
      const float* p = (const float*)W + (size_t)(r0 + r) * Dc + c0 + c;
      float4 f0 = *(const float4*)p, f1 = *(const float4*)(p + 4);
      pk[0] = (short)f2bf(f0.x * scale); pk[1] = (short)f2bf(f0.y * scale);
      pk[2] = (short)f2bf(f0.z * scale); pk[3] = (short)f2bf(f0.w * scale);
      pk[4] = (short)f2bf(f1.x * scale); pk[5] = (short)f2bf(f1.y * scale);
      pk[6] = (short)f2bf(f1.z * scale); pk[7] = (short)f2bf(f1.w * scale);
    }
    *(bfrag*)(&ts[r][c]) = pk;
  }
  __syncthreads();
  for (int i = 0; i < 2; ++i) {
    int ch = tid + i * 256;
    int n = ch >> 3, k = (ch & 7) * 8;
    u16 tmp[8] __attribute__((aligned(16)));
    for (int j = 0; j < 8; ++j) tmp[j] = (u16)ts[k + j][n];
    *(uint4*)(Wt + (size_t)(c0 + n) * Dc + r0 + k) = *(const uint4*)tmp;
  }
}

// ---------------- GEMM: C(MxN) = A(MxK) @ Bt(NxK)^T + bias ----------------------
// One-barrier async dbuf K-loop; optional z-fused triple launch (QKV).
#define BM 128
#define BN 128
#define BK 32

#define GEMM_STAGE(bufI)                                                          \
  {                                                                               \
    gl_lds16(bgp0, &Bs[bufI][wave * 16][0]);                                      \
    gl_lds16(bgp1, &Bs[bufI][wave * 16 + 64][0]);                                 \
    bgp0 += BK; bgp1 += BK;                                                       \
    if (a_bf) {                                                                   \
      gl_lds16(agp0, &As[bufI][wave * 16][0]);                                    \
      gl_lds16(agp1, &As[bufI][wave * 16 + 64][0]);                               \
      agp0 += BK; agp1 += BK;                                                     \
    } else {                                                                      \
      for (int i_ = 0; i_ < 2; ++i_) {                                            \
        int ch_ = tid + i_ * 256;                                                 \
        int r_ = ch_ >> 2, kc_ = (ch_ & 3) * 8;                                   \
        const float* p_ = (const float*)Araw + (size_t)(bm0 + r_) * K + ksf + kc_;\
        float4 f0_ = *(const float4*)p_, f1_ = *(const float4*)(p_ + 4);          \
        uint4 st_;                                                                \
        st_.x = pkbf(f0_.x, f0_.y); st_.y = pkbf(f0_.z, f0_.w);                   \
        st_.z = pkbf(f1_.x, f1_.y); st_.w = pkbf(f1_.z, f1_.w);                   \
        *(uint4*)(&As[bufI][r_][kc_]) = st_;                                      \
      }                                                                           \
    }                                                                             \
    ksf += BK;                                                                    \
  }

__global__ __launch_bounds__(256) void gemm_bt(
    const void* __restrict__ Araw, const u16* __restrict__ Bt,
    const float* __restrict__ bias, void* __restrict__ Cout, u16* __restrict__ VtOut,
    const int* __restrict__ flags, int M, int N, int K,
    int a_mode /*1=A always bf16*/, int c_mode /*0=bf16 1=per-flags 2=V^T*/,
    int qkv /*1 = triple launch via blockIdx.z*/) {
  __shared__ __align__(16) u16 As[2][BM][BK];  // 2 x 8 KB
  __shared__ __align__(16) u16 Bs[2][BN][BK];
  if (qkv) {
    const int z = blockIdx.z;
    Araw = (const void*)((const u16*)Araw + (size_t)z * Bc * Sc * Dc);
    Bt += (size_t)z * Dc * Dc;
    bias += z * Dc;
    if (z == 2) { c_mode = 2; Cout = (void*)VtOut; }
    else Cout = (void*)((u16*)Cout + (size_t)z * Bc * Sc * Dc);
  }
  const int tid = threadIdx.x;
  const int lane = tid & 63, wave = tid >> 6;
  const int lr = lane & 15, lq = lane >> 4;
  const int ntiles = N >> 7;
  const int band = (M >> 7) >> 3;
  const int L = blockIdx.x;
  const int mt = (L & 7) * band + ((L >> 3) / ntiles);
  const int nt = (L >> 3) % ntiles;
  const int bm0 = mt * BM, bn0 = nt * BN;
  const int wm = (wave >> 1) * 64, wn = (wave & 1) * 64;
  const int a_bf = a_mode ? 1 : flags[0];
  const int srow = lane >> 2;
  const int schunk = lane & 3;
  const u16* bgp0 = Bt + (size_t)(bn0 + wave * 16 + srow) * K + schunk * 8;
  const u16* bgp1 = bgp0 + (size_t)64 * K;
  const u16* agp0 = (const u16*)Araw + (size_t)(bm0 + wave * 16 + srow) * K + schunk * 8;
  const u16* agp1 = agp0 + (size_t)64 * K;
  int ksf = 0;
  f32x4 acc[4][4] = {};
  GEMM_STAGE(0);
  __syncthreads();
  const int NIT = K / BK;
#pragma unroll 2
  for (int it = 0; it < NIT; ++it) {
    const int p = it & 1;
    if (it + 1 < NIT) { GEMM_STAGE(p ^ 1); }
    bfrag af[4], bf[4];
    for (int mi = 0; mi < 4; ++mi) af[mi] = *(const bfrag*)(&As[p][wm + mi * 16 + lr][lq * 8]);
    for (int nj = 0; nj < 4; ++nj) bf[nj] = *(const bfrag*)(&Bs[p][wn + nj * 16 + lr][lq * 8]);
    for (int mi = 0; mi < 4; ++mi)
      for (int nj = 0; nj < 4; ++nj)
        acc[mi][nj] = __builtin_amdgcn_mfma_f32_16x16x32_bf16(af[mi], bf[nj], acc[mi][nj], 0, 0, 0);
    __syncthreads();
  }
  float bcol[4];
  for (int nj = 0; nj < 4; ++nj) bcol[nj] = bias[bn0 + wn + nj * 16 + lr];
  if (c_mode == 2) {
    // write V^T: dst[((b*H+h)*64 + d)][s], 4 consecutive s per lane = 8B store
    u16* VT = (u16*)Cout;
    for (int mi = 0; mi < 4; ++mi)
      for (int nj = 0; nj < 4; ++nj) {
        int row = bm0 + wm + mi * 16 + lq * 4;       // s base (4 consecutive)
        int col = bn0 + wn + nj * 16 + lr;           // h*64+d
        float v0 = acc[mi][nj][0] + bcol[nj], v1 = acc[mi][nj][1] + bcol[nj];
        float v2 = acc[mi][nj][2] + bcol[nj], v3 = acc[mi][nj][3] + bcol[nj];
        uint2 st;
        st.x = pkbf(v0, v1);
        st.y = pkbf(v2, v3);
        size_t drow = (size_t)((row >> 11) * Hc + (col >> 6)) * DHc + (col & 63);
        *(uint2*)(VT + drow * Sc + (row & (Sc - 1))) = st;
      }
  } else {
    const int outbf = (c_mode == 0) ? 1 : flags[0];
    for (int mi = 0; mi < 4; ++mi)
      for (int r = 0; r < 4; ++r) {
        int row = bm0 + wm + mi * 16 + lq * 4 + r;
        for (int nj = 0; nj < 4; ++nj) {
          int col = bn0 + wn + nj * 16 + lr;
          float v = acc[mi][nj][r] + bcol[nj];
          if (outbf) ((u16*)Cout)[(size_t)row * N + col] = f2bf(v);
          else ((float*)Cout)[(size_t)row * N + col] = v;
        }
      }
  }
}

// ---------------- flash attention: cross-tile software pipeline (R4 config) ------
// S^T = K·Q^T + maskbias (LDS maskL as direct MFMA C-in); p = exp2(s) direct via
// single-instruction v_exp_f32; pack via single v_cvt_pk_bf16_f32.
// PV + rowsum at K=32 via permlane fragment redistribution.
// Pipeline: per iteration, S(kt+1) MFMAs are issued BEFORE softmax+PV(kt).
__global__ __launch_bounds__(256) void attn_kernel(
    const u16* __restrict__ Q, const u16* __restrict__ K,
    const u16* __restrict__ Vt, const float* __restrict__ maskf,
    u16* __restrict__ Aout) {
  __shared__ __align__(16) u16 Ks[2][64][64];   // 2 x 8 KB, chunk^(row&7) swizzle
  __shared__ __align__(16) u16 Vts[2][64][64];  // 2 x 8 KB
  __shared__ float maskL[Sc];                   // 8 KB
  const int tid = threadIdx.x;
  const int lane = tid & 63, wave = tid >> 6;
  const int lr = lane & 15, lq = lane >> 4;
  const int bh = blockIdx.x;                    // all q-tiles of (b,h) -> same XCD
  const int b = bh >> 4, h = bh & 15;
  const int q0 = blockIdx.y * 128;
  const int wq = wave * 32;
  const int rr0 = wave * 16 + (lane >> 3);
  const int rr1 = rr0 + 8;
  const int cc = lane & 7;
  const u16* kg0 = K + (size_t)(b * Sc + rr0) * Dc + h * DHc + ((cc ^ (rr0 & 7)) * 8);
  const u16* kg1 = K + (size_t)(b * Sc + rr1) * Dc + h * DHc + ((cc ^ (rr1 & 7)) * 8);
  const u16* vg0 = Vt + (size_t)((b * Hc + h) * DHc + rr0) * Sc + ((cc ^ (rr0 & 7)) * 8);
  const u16* vg1 = Vt + (size_t)((b * Hc + h) * DHc + rr1) * Sc + ((cc ^ (rr1 & 7)) * 8);
#define STAGE_K(bufI)                                         \
  {                                                           \
    gl_lds16(kg0, &Ks[bufI][wave * 16][0]);                   \
    gl_lds16(kg1, &Ks[bufI][wave * 16 + 8][0]);               \
    kg0 += (size_t)64 * Dc; kg1 += (size_t)64 * Dc;           \
  }
#define STAGE_V(bufI)                                         \
  {                                                           \
    gl_lds16(vg0, &Vts[bufI][wave * 16][0]);                  \
    gl_lds16(vg1, &Vts[bufI][wave * 16 + 8][0]);              \
    vg0 += 64; vg1 += 64;                                     \
  }
  bfrag qf[2][2];
  for (int mi = 0; mi < 2; ++mi)
    for (int ks = 0; ks < 2; ++ks)
      qf[mi][ks] = *(const bfrag*)(Q + (size_t)(b * Sc + q0 + wq + mi * 16 + lr) * Dc +
                                   h * DHc + ks * 32 + lq * 8);
  f32x4 oacc[2][4] = {};  // O^T
  f32x4 oext[2] = {};     // row-sum accumulator (every reg = rsum(q=lr))
  FB ones;
  ones.w[0] = 0x3F803F80u; ones.w[1] = 0x3F803F80u; ones.w[2] = 0x3F803F80u; ones.w[3] = 0x3F803F80u;
  const int lrx = lr & 7;
  const int NT = Sc / 64;
  f32x4 saccA[2][4], saccB[2][4];

// S^T for tile ktt from Kbuf[KB] into DST; mask bias is the first MFMA's C-in.
#define SBLOCK(KB, ktt, DST)                                                                  \
  {                                                                                           \
    for (int nk = 0; nk < 4; ++nk) {                                                          \
      const int kr = nk * 16 + lr;                                                            \
      bfrag kf0 = *(const bfrag*)(&Ks[KB][kr][(lq ^ lrx) * 8]);                               \
      bfrag kf1 = *(const bfrag*)(&Ks[KB][kr][((4 + lq) ^ lrx) * 8]);                         \
      f32x4 mk = *(const f32x4*)(&maskL[(ktt) * 64 + nk * 16 + lq * 4]);                      \
      for (int mi = 0; mi < 2; ++mi) {                                                        \
        f32x4 t = __builtin_amdgcn_mfma_f32_16x16x32_bf16(kf0, qf[mi][0], mk, 0, 0, 0);       \
        DST[mi][nk] = __builtin_amdgcn_mfma_f32_16x16x32_bf16(kf1, qf[mi][1], t, 0, 0, 0);    \
      }                                                                                       \
    }                                                                                         \
  }

// softmax + PV + rowsum for tile in SRC, V from Vbuf[VB].
#define PVBLOCK(VB, SRC)                                                                      \
  {                                                                                           \
    for (int c = 0; c < 2; ++c) {                                                             \
      FB pb[2];                                                                               \
      for (int mi = 0; mi < 2; ++mi) {                                                        \
        const f32x4 s0 = SRC[mi][2 * c];                                                      \
        const f32x4 s1 = SRC[mi][2 * c + 1];                                                  \
        u32 w0 = pkbf(EXP2(s0[0]), EXP2(s0[1]));                                              \
        u32 w1 = pkbf(EXP2(s0[2]), EXP2(s0[3]));                                              \
        u32 w2 = pkbf(EXP2(s1[0]), EXP2(s1[1]));                                              \
        u32 w3 = pkbf(EXP2(s1[2]), EXP2(s1[3]));                                              \
        pl32swap(w0, w2); pl16swap(w0, w2);                                                   \
        pl32swap(w1, w3); pl16swap(w1, w3);                                                   \
        pb[mi].w[0] = w0; pb[mi].w[1] = w1; pb[mi].w[2] = w2; pb[mi].w[3] = w3;               \
      }                                                                                       \
      for (int nd = 0; nd < 4; ++nd) {                                                        \
        const int dr = nd * 16 + lr;                                                          \
        const bfrag vb = *(const bfrag*)(&Vts[VB][dr][((4 * c + lq) ^ lrx) * 8]);             \
        oacc[0][nd] = __builtin_amdgcn_mfma_f32_16x16x32_bf16(vb, pb[0].f, oacc[0][nd], 0, 0, 0); \
        oacc[1][nd] = __builtin_amdgcn_mfma_f32_16x16x32_bf16(vb, pb[1].f, oacc[1][nd], 0, 0, 0); \
      }                                                                                       \
      oext[0] = __builtin_amdgcn_mfma_f32_16x16x32_bf16(ones.f, pb[0].f, oext[0], 0, 0, 0);   \
      oext[1] = __builtin_amdgcn_mfma_f32_16x16x32_bf16(ones.f, pb[1].f, oext[1], 0, 0, 0);   \
    }                                                                                         \
  }

  // ---- prologue: stage K0,V0; fill maskL; barrier; stage K1; compute S(0) ----
  STAGE_K(0);
  STAGE_V(0);
  {
    const float4* ms = (const float4*)(maskf + b * Sc);
    for (int i = tid; i < Sc / 4; i += 256) ((float4*)maskL)[i] = ms[i];
  }
  __syncthreads();
  STAGE_K(1);
  SBLOCK(0, 0, saccA);

  for (int kt = 0; kt < NT; kt += 2) {
    // ---- even body: S(kt) in saccA ----
    __syncthreads();                 // drains K(kt+1), V(kt); all waves done with Kbuf0, Vbuf1
    if (kt + 2 < NT) STAGE_K(0);     // K(kt+2)
    STAGE_V(1);                      // V(kt+1)  (kt+1 <= NT-1 always here)
    SBLOCK(1, kt + 1, saccB);        // S(kt+1) MFMAs issued before softmax(kt)
    PVBLOCK(0, saccA);               // softmax+PV(kt) overlaps S(kt+1)
    // ---- odd body: S(kt+1) in saccB ----
    __syncthreads();                 // drains K(kt+2), V(kt+1)
    if (kt + 3 < NT) STAGE_K(1);     // K(kt+3)
    if (kt + 2 < NT) {
      STAGE_V(0);                    // V(kt+2)
      SBLOCK(0, kt + 2, saccA);      // S(kt+2)
    }
    PVBLOCK(1, saccB);               // softmax+PV(kt+1)
  }

  for (int mi = 0; mi < 2; ++mi) {
    float inv = 1.0f / oext[mi][0];
    u16* rowp = Aout + (size_t)(b * Sc + q0 + wq + mi * 16 + lr) * Dc + h * DHc;
    for (int nd = 0; nd < 4; ++nd) {
      float o0 = oacc[mi][nd][0] * inv, o1 = oacc[mi][nd][1] * inv;
      float o2 = oacc[mi][nd][2] * inv, o3 = oacc[mi][nd][3] * inv;
      uint2 st;
      st.x = pkbf(o0, o1);
      st.y = pkbf(o2, o3);
      *(uint2*)(rowp + nd * 16 + lq * 4) = st;
    }
  }
#undef STAGE_K
#undef STAGE_V
#undef SBLOCK
#undef PVBLOCK
}

extern "C" void kernel_launch(void* const* d_in, const int* in_sizes, int n_in,
                              void* d_out, int out_size, void* d_ws, size_t ws_size,
                              hipStream_t stream) {
  (void)in_sizes; (void)n_in; (void)out_size;
  char* ws = (char*)d_ws;
  int* flags = (int*)ws;                              // 256 B
  float* maskf = (float*)(ws + 256);                  // 32 KB
  float* biasf = (float*)(ws + 256 + Bc * Sc * 4);    // 16 KB
  u16* WqT = (u16*)(ws + 65536);
  u16* WkT = WqT + (size_t)Dc * Dc;
  u16* WvT = WkT + (size_t)Dc * Dc;
  u16* WoT = WvT + (size_t)Dc * Dc;
  u16* Qb  = WoT + (size_t)Dc * Dc;
  u16* Kb  = Qb + (size_t)Bc * Sc * Dc;
  u16* Vb  = Kb + (size_t)Bc * Sc * Dc;               // unused (V^T written directly)
  u16* Vtb = Vb + (size_t)Bc * Sc * Dc;
  u16* Ab  = Vtb + (size_t)Bc * Sc * Dc;
  u16* qbf = Ab + (size_t)Bc * Sc * Dc;               // bf16 copies of inputs (contiguous q,k,v)
  u16* kbf = qbf + (size_t)Bc * Sc * Dc;
  u16* vbf = kbf + (size_t)Bc * Sc * Dc;
  const size_t need = (size_t)((char*)(vbf + (size_t)Bc * Sc * Dc) - ws);
  const bool have_cvt = ws_size >= need;
  const int cvtBlocks = have_cvt ? 3 * 4096 : 0;

  prep_flags_k<<<1, 256, 0, stream>>>(d_in[0], d_in[3], flags);
  aux_all<<<48 + cvtBlocks + 1024, 256, 0, stream>>>(
      d_in[4], d_in[6], d_in[8], d_in[10], WqT, WkT, WvT, WoT,
      d_in[0], d_in[1], d_in[2], qbf, kbf, vbf,
      d_in[3], d_in[5], d_in[7], d_in[9], d_in[11],
      flags, maskf, biasf, cvtBlocks);
  const int nblk = (Bc * Sc / BM) * (Dc / BN);        // 512
  if (have_cvt) {
    // z-fused QKV: z=0 -> Qb, z=1 -> Kb, z=2 -> V^T into Vtb
    gemm_bt<<<dim3(nblk, 1, 3), 256, 0, stream>>>(qbf, WqT, biasf, Qb, Vtb, flags,
                                                  Bc * Sc, Dc, Dc, 1, 0, 1);
  } else {
    gemm_bt<<<nblk, 256, 0, stream>>>(d_in[0], WqT, biasf, Qb, nullptr, flags,
                                      Bc * Sc, Dc, Dc, 0, 0, 0);
    gemm_bt<<<nblk, 256, 0, stream>>>(d_in[1], WkT, biasf + Dc, Kb, nullptr, flags,
                                      Bc * Sc, Dc, Dc, 0, 0, 0);
    gemm_bt<<<nblk, 256, 0, stream>>>(d_in[2], WvT, biasf + 2 * Dc, Vtb, nullptr, flags,
                                      Bc * Sc, Dc, Dc, 0, 2, 0);
  }
  attn_kernel<<<dim3(64, 16), 256, 0, stream>>>(Qb, Kb, Vtb, maskf, Ab);
  gemm_bt<<<nblk, 256, 0, stream>>>(Ab, WoT, biasf + 3 * Dc, d_out, nullptr, flags,
                                    Bc * Sc, Dc, Dc, 1, 1, 0);
}

// Round 10
// 346.820 us; speedup vs baseline: 1.1808x; 1.0053x over previous
//
#include <hip/hip_runtime.h>
#include <hip/hip_bf16.h>

#define Bc 4
#define Sc 2048
#define Dc 1024
#define Hc 16
#define DHc 64

typedef unsigned short u16;
typedef unsigned int u32;
typedef __attribute__((ext_vector_type(8))) short bfrag;
typedef __attribute__((ext_vector_type(4))) float f32x4;

#define SCALE_Q 0.18033688011112042f  /* 0.125 * log2(e): exp2-domain softmax */

// single-instruction hardware exp2 (v_exp_f32 computes 2^x).
__device__ __forceinline__ float exp2_hw(float x) {
  float r;
  asm("v_exp_f32 %0, %1" : "=v"(r) : "v"(x));
  return r;
}
#define EXP2(x) exp2_hw(x)

__device__ __forceinline__ u16 f2bf(float f) {
  u32 u = __float_as_uint(f);
  return (u16)((u + 0x7fffu + ((u >> 16) & 1u)) >> 16);
}
__device__ __forceinline__ float bf2f(u16 h) { return __uint_as_float(((u32)h) << 16); }

// packed f32x2 -> bf16x2: single v_cvt_pk_bf16_f32 (RNE).
__device__ __forceinline__ u32 pkbf(float a, float b) {
  u32 r;
  asm("v_cvt_pk_bf16_f32 %0, %1, %2" : "=v"(r) : "v"(a), "v"(b));
  return r;
}

union FB { bfrag f; u32 w[4]; };

// gfx950 fragment-redistribution swaps: both operands are read-write.
#if __has_builtin(__builtin_amdgcn_permlane32_swap) && __has_builtin(__builtin_amdgcn_permlane16_swap)
typedef __attribute__((ext_vector_type(2))) unsigned int u32x2;
__device__ __forceinline__ void pl32swap(u32& x, u32& y) {
  u32x2 r = __builtin_amdgcn_permlane32_swap(x, y, false, false);
  x = r.x; y = r.y;
}
__device__ __forceinline__ void pl16swap(u32& x, u32& y) {
  u32x2 r = __builtin_amdgcn_permlane16_swap(x, y, false, false);
  x = r.x; y = r.y;
}
#else
__device__ __forceinline__ void pl32swap(u32& x, u32& y) {
  asm volatile("v_permlane32_swap_b32 %0, %1" : "+v"(x), "+v"(y));
}
__device__ __forceinline__ void pl16swap(u32& x, u32& y) {
  asm volatile("v_permlane16_swap_b32 %0, %1" : "+v"(x), "+v"(y));
}
#endif

// async global->LDS, 16B per lane, dest = wave-uniform base + lane*16
__device__ __forceinline__ void gl_lds16(const u16* g, u16* l) {
  __builtin_amdgcn_global_load_lds(
      (const __attribute__((address_space(1))) unsigned int*)g,
      (__attribute__((address_space(3))) unsigned int*)l, 16, 0, 0);
}

// ---------------- flags only: dtype + mask layout detect (1 tiny block) ----------
__global__ __launch_bounds__(256) void prep_flags_k(
    const void* __restrict__ qsrc, const void* __restrict__ mask,
    int* __restrict__ flags) {
  __shared__ int c_bf, c_ni, c_nf;
  const int tid = threadIdx.x;
  if (tid == 0) { c_bf = 0; c_ni = 0; c_nf = 0; }
  __syncthreads();
  u32 w = ((const u32*)qsrc)[tid];
  int e = (int)((w >> 7) & 0xffu);
  if (e >= 118 && e <= 130) atomicAdd(&c_bf, 1);
  int ni = 0, nf = 0;
  for (int i = tid; i < 2048; i += 256) {
    u32 v = ((const u32*)mask)[i];
    if (v > 1u) ni = 1;
    if (v != 0u && v != 0x3f800000u) nf = 1;
  }
  if (ni) atomicAdd(&c_ni, 1);
  if (nf) atomicAdd(&c_nf, 1);
  __syncthreads();
  if (tid == 0) {
    flags[0] = (c_bf > 128) ? 1 : 0;
    flags[1] = (c_ni == 0) ? 0 : ((c_nf == 0) ? 2 : 1); // 0=int32 1=byte 2=f32
  }
}

// ---------------- fused aux: prep-fill + input cvt + weight transposes -----------
// One launch, role by blockIdx range (each block uniform-role; in-role barrier ok):
//   [0, 48)                 prep-fill: maskf (8192) + biasf (4096), 256 elem/blk
//   [48, 48+cvtBlocks)      cvt3: f32->bf16 (or copy) of q,k,v
//   [48+cvtBlocks, +1024)   transpose_all: 4 weights, 64x64 tiles
__global__ __launch_bounds__(256) void aux_all(
    const void* __restrict__ W0, const void* __restrict__ W1,
    const void* __restrict__ W2, const void* __restrict__ W3,
    u16* __restrict__ D0, u16* __restrict__ D1, u16* __restrict__ D2,
    u16* __restrict__ D3,
    const void* __restrict__ s0, const void* __restrict__ s1,
    const void* __restrict__ s2,
    u16* __restrict__ d0, u16* __restrict__ d1, u16* __restrict__ d2,
    const void* __restrict__ mask,
    const void* __restrict__ bq, const void* __restrict__ bk,
    const void* __restrict__ bv, const void* __restrict__ bo,
    const int* __restrict__ flags, float* __restrict__ maskf,
    float* __restrict__ biasf, int cvtBlocks) {
  __shared__ short ts[64][72];
  const int tid = threadIdx.x;
  const int bb = blockIdx.x;
  const int isbf = flags[0];
  if (bb < 48) {
    // ---- prep-fill ----
    int i = bb * 256 + tid;
    if (i < Bc * Sc) {
      const int layout = flags[1];
      int mv;
      if (layout == 0) mv = ((const int*)mask)[i];
      else if (layout == 1) mv = (int)((const unsigned char*)mask)[i];
      else mv = (((const u32*)mask)[i] != 0u) ? 1 : 0;
      maskf[i] = mv ? -1e30f : 0.0f;  // True = padding = excluded
    } else {
      int j = i - Bc * Sc;            // 0..4095
      int wsel = j >> 10, o = j & 1023;
      const void* bp = wsel == 0 ? bq : (wsel == 1 ? bk : (wsel == 2 ? bv : bo));
      float sc = (wsel == 0) ? SCALE_Q : 1.0f;  // fold softmax scale into Q bias
      biasf[j] = (isbf ? bf2f(((const u16*)bp)[o]) : ((const float*)bp)[o]) * sc;
    }
    return;
  }
  if (bb < 48 + cvtBlocks) {
    // ---- cvt3 ----
    int idx = bb - 48;
    int zy = idx >> 12, x = idx & 4095;         // cvtBlocks = 3*4096
    const void* s = zy == 0 ? s0 : (zy == 1 ? s1 : s2);
    u16* d = zy == 0 ? d0 : (zy == 1 ? d1 : d2);
    size_t e = ((size_t)x * 256 + tid) * 8;
    if (isbf) {
      *(uint4*)(d + e) = *(const uint4*)((const u16*)s + e);
    } else {
      const float* p = (const float*)s + e;
      float4 f0 = *(const float4*)p, f1 = *(const float4*)(p + 4);
      uint4 st;
      st.x = pkbf(f0.x, f0.y); st.y = pkbf(f0.z, f0.w);
      st.z = pkbf(f1.x, f1.y); st.w = pkbf(f1.z, f1.w);
      *(uint4*)(d + e) = st;
    }
    return;
  }
  // ---- weight transpose ----
  const int t = bb - (48 + cvtBlocks);
  const int z = t >> 8;
  const void* W = z == 0 ? W0 : (z == 1 ? W1 : (z == 2 ? W2 : W3));
  u16* Wt = z == 0 ? D0 : (z == 1 ? D1 : (z == 2 ? D2 : D3));
  const float scale = (z == 0) ? SCALE_Q : 1.0f;
  const int r0 = ((t >> 4) & 15) * 64, c0 = (t & 15) * 64;
  for (int i = 0; i < 2; ++i) {
    int ch = tid + i * 256;
    int r = ch >> 3, c = (ch & 7) * 8;
    bfrag pk;
    if (isbf) {
      uint4 v = *(const uint4*)((const u16*)W + (size_t)(r0 + r) * Dc + c0 + c);
      const u16* pv = (const u16*)&v;
      for (int j = 0; j < 8; ++j) pk[j] = (short)f2bf(bf2f(pv[j]) * scale);
    } else {
      const float* p = (const float*)W + (size_t)(r0 + r) * Dc + c0 + c;
      float4 f0 = *(const float4*)p, f1 = *(const float4*)(p + 4);
      pk[0] = (short)f2bf(f0.x * scale); pk[1] = (short)f2bf(f0.y * scale);
      pk[2] = (short)f2bf(f0.z * scale); pk[3] = (short)f2bf(f0.w * scale);
      pk[4] = (short)f2bf(f1.x * scale); pk[5] = (short)f2bf(f1.y * scale);
      pk[6] = (short)f2bf(f1.z * scale); pk[7] = (short)f2bf(f1.w * scale);
    }
    *(bfrag*)(&ts[r][c]) = pk;
  }
  __syncthreads();
  for (int i = 0; i < 2; ++i) {
    int ch = tid + i * 256;
    int n = ch >> 3, k = (ch & 7) * 8;
    u16 tmp[8] __attribute__((aligned(16)));
    for (int j = 0; j < 8; ++j) tmp[j] = (u16)ts[k + j][n];
    *(uint4*)(Wt + (size_t)(c0 + n) * Dc + r0 + k) = *(const uint4*)tmp;
  }
}

// ---------------- GEMM: C(MxN) = A(MxK) @ Bt(NxK)^T + bias ----------------------
// One-barrier async dbuf K-loop; optional z-fused triple launch (QKV).
// do_mask: zero output rows (c_mode 0/1) / V^T columns (c_mode 2) where
// maskf[row] != 0 -- bakes key_padding_mask into K and V so the attention
// kernel needs no mask bias (masked key: s=0 -> p=1, PV contrib 0, rowsum
// corrected by per-batch masked count).
#define BM 128
#define BN 128
#define BK 32

#define GEMM_STAGE(bufI)                                                          \
  {                                                                               \
    gl_lds16(bgp0, &Bs[bufI][wave * 16][0]);                                      \
    gl_lds16(bgp1, &Bs[bufI][wave * 16 + 64][0]);                                 \
    bgp0 += BK; bgp1 += BK;                                                       \
    if (a_bf) {                                                                   \
      gl_lds16(agp0, &As[bufI][wave * 16][0]);                                    \
      gl_lds16(agp1, &As[bufI][wave * 16 + 64][0]);                               \
      agp0 += BK; agp1 += BK;                                                     \
    } else {                                                                      \
      for (int i_ = 0; i_ < 2; ++i_) {                                            \
        int ch_ = tid + i_ * 256;                                                 \
        int r_ = ch_ >> 2, kc_ = (ch_ & 3) * 8;                                   \
        const float* p_ = (const float*)Araw + (size_t)(bm0 + r_) * K + ksf + kc_;\
        float4 f0_ = *(const float4*)p_, f1_ = *(const float4*)(p_ + 4);          \
        uint4 st_;                                                                \
        st_.x = pkbf(f0_.x, f0_.y); st_.y = pkbf(f0_.z, f0_.w);                   \
        st_.z = pkbf(f1_.x, f1_.y); st_.w = pkbf(f1_.z, f1_.w);                   \
        *(uint4*)(&As[bufI][r_][kc_]) = st_;                                      \
      }                                                                           \
    }                                                                             \
    ksf += BK;                                                                    \
  }

__global__ __launch_bounds__(256) void gemm_bt(
    const void* __restrict__ Araw, const u16* __restrict__ Bt,
    const float* __restrict__ bias, void* __restrict__ Cout, u16* __restrict__ VtOut,
    const float* __restrict__ maskf, const int* __restrict__ flags, int M, int N, int K,
    int a_mode /*1=A always bf16*/, int c_mode /*0=bf16 1=per-flags 2=V^T*/,
    int qkv /*1 = triple launch via blockIdx.z*/, int do_mask) {
  __shared__ __align__(16) u16 As[2][BM][BK];  // 2 x 8 KB
  __shared__ __align__(16) u16 Bs[2][BN][BK];
  if (qkv) {
    const int z = blockIdx.z;
    Araw = (const void*)((const u16*)Araw + (size_t)z * Bc * Sc * Dc);
    Bt += (size_t)z * Dc * Dc;
    bias += z * Dc;
    if (z == 2) { c_mode = 2; Cout = (void*)VtOut; }
    else Cout = (void*)((u16*)Cout + (size_t)z * Bc * Sc * Dc);
    do_mask = (z >= 1) ? 1 : 0;   // mask K rows and V^T columns, not Q
  }
  const int tid = threadIdx.x;
  const int lane = tid & 63, wave = tid >> 6;
  const int lr = lane & 15, lq = lane >> 4;
  const int ntiles = N >> 7;
  const int band = (M >> 7) >> 3;
  const int L = blockIdx.x;
  const int mt = (L & 7) * band + ((L >> 3) / ntiles);
  const int nt = (L >> 3) % ntiles;
  const int bm0 = mt * BM, bn0 = nt * BN;
  const int wm = (wave >> 1) * 64, wn = (wave & 1) * 64;
  const int a_bf = a_mode ? 1 : flags[0];
  const int srow = lane >> 2;
  const int schunk = lane & 3;
  const u16* bgp0 = Bt + (size_t)(bn0 + wave * 16 + srow) * K + schunk * 8;
  const u16* bgp1 = bgp0 + (size_t)64 * K;
  const u16* agp0 = (const u16*)Araw + (size_t)(bm0 + wave * 16 + srow) * K + schunk * 8;
  const u16* agp1 = agp0 + (size_t)64 * K;
  int ksf = 0;
  f32x4 acc[4][4] = {};
  GEMM_STAGE(0);
  __syncthreads();
  const int NIT = K / BK;
#pragma unroll 2
  for (int it = 0; it < NIT; ++it) {
    const int p = it & 1;
    if (it + 1 < NIT) { GEMM_STAGE(p ^ 1); }
    bfrag af[4], bf[4];
    for (int mi = 0; mi < 4; ++mi) af[mi] = *(const bfrag*)(&As[p][wm + mi * 16 + lr][lq * 8]);
    for (int nj = 0; nj < 4; ++nj) bf[nj] = *(const bfrag*)(&Bs[p][wn + nj * 16 + lr][lq * 8]);
    for (int mi = 0; mi < 4; ++mi)
      for (int nj = 0; nj < 4; ++nj)
        acc[mi][nj] = __builtin_amdgcn_mfma_f32_16x16x32_bf16(af[mi], bf[nj], acc[mi][nj], 0, 0, 0);
    __syncthreads();
  }
  float bcol[4];
  for (int nj = 0; nj < 4; ++nj) bcol[nj] = bias[bn0 + wn + nj * 16 + lr];
  if (c_mode == 2) {
    // write V^T: dst[((b*H+h)*64 + d)][s], 4 consecutive s per lane = 8B store
    u16* VT = (u16*)Cout;
    for (int mi = 0; mi < 4; ++mi) {
      int row = bm0 + wm + mi * 16 + lq * 4;         // s base (4 consecutive)
      float k0 = 1.0f, k1 = 1.0f, k2 = 1.0f, k3 = 1.0f;
      if (do_mask) {
        const float4 mv4 = *(const float4*)(maskf + row);
        k0 = (mv4.x != 0.0f) ? 0.0f : 1.0f;
        k1 = (mv4.y != 0.0f) ? 0.0f : 1.0f;
        k2 = (mv4.z != 0.0f) ? 0.0f : 1.0f;
        k3 = (mv4.w != 0.0f) ? 0.0f : 1.0f;
      }
      for (int nj = 0; nj < 4; ++nj) {
        int col = bn0 + wn + nj * 16 + lr;           // h*64+d
        float v0 = (acc[mi][nj][0] + bcol[nj]) * k0, v1 = (acc[mi][nj][1] + bcol[nj]) * k1;
        float v2 = (acc[mi][nj][2] + bcol[nj]) * k2, v3 = (acc[mi][nj][3] + bcol[nj]) * k3;
        uint2 st;
        st.x = pkbf(v0, v1);
        st.y = pkbf(v2, v3);
        size_t drow = (size_t)((row >> 11) * Hc + (col >> 6)) * DHc + (col & 63);
        *(uint2*)(VT + drow * Sc + (row & (Sc - 1))) = st;
      }
    }
  } else {
    const int outbf = (c_mode == 0) ? 1 : flags[0];
    for (int mi = 0; mi < 4; ++mi)
      for (int r = 0; r < 4; ++r) {
        int row = bm0 + wm + mi * 16 + lq * 4 + r;
        float keep = (do_mask && maskf[row] != 0.0f) ? 0.0f : 1.0f;
        for (int nj = 0; nj < 4; ++nj) {
          int col = bn0 + wn + nj * 16 + lr;
          float v = (acc[mi][nj][r] + bcol[nj]) * keep;
          if (outbf) ((u16*)Cout)[(size_t)row * N + col] = f2bf(v);
          else ((float*)Cout)[(size_t)row * N + col] = v;
        }
      }
  }
}

// ---------------- flash attention: mask-free inner loop (mask baked into K/V) ----
// S^T = K·Q^T (C-in = zero quad); masked keys have K row = 0 -> s = 0 -> p = 1,
// PV contribution 0 (V^T column zeroed), rowsum over-counts by nm[b] (counted in
// prologue via LDS atomic, subtracted before reciprocal). p = exp2(s) via
// v_exp_f32; pack via v_cvt_pk_bf16_f32; PV + rowsum at K=32 via permlane
// fragment redistribution. Per iteration, S(kt+1) MFMAs are issued BEFORE
// softmax+PV(kt) (cross-tile pipeline).
__global__ __launch_bounds__(256) void attn_kernel(
    const u16* __restrict__ Q, const u16* __restrict__ K,
    const u16* __restrict__ Vt, const float* __restrict__ maskf,
    u16* __restrict__ Aout) {
  __shared__ __align__(16) u16 Ks[2][64][64];   // 2 x 8 KB, chunk^(row&7) swizzle
  __shared__ __align__(16) u16 Vts[2][64][64];  // 2 x 8 KB
  __shared__ int nmS;
  const int tid = threadIdx.x;
  const int lane = tid & 63, wave = tid >> 6;
  const int lr = lane & 15, lq = lane >> 4;
  const int bh = blockIdx.x;                    // all q-tiles of (b,h) -> same XCD
  const int b = bh >> 4, h = bh & 15;
  const int q0 = blockIdx.y * 128;
  const int wq = wave * 32;
  const int rr0 = wave * 16 + (lane >> 3);
  const int rr1 = rr0 + 8;
  const int cc = lane & 7;
  const u16* kg0 = K + (size_t)(b * Sc + rr0) * Dc + h * DHc + ((cc ^ (rr0 & 7)) * 8);
  const u16* kg1 = K + (size_t)(b * Sc + rr1) * Dc + h * DHc + ((cc ^ (rr1 & 7)) * 8);
  const u16* vg0 = Vt + (size_t)((b * Hc + h) * DHc + rr0) * Sc + ((cc ^ (rr0 & 7)) * 8);
  const u16* vg1 = Vt + (size_t)((b * Hc + h) * DHc + rr1) * Sc + ((cc ^ (rr1 & 7)) * 8);
#define STAGE_K(bufI)                                         \
  {                                                           \
    gl_lds16(kg0, &Ks[bufI][wave * 16][0]);                   \
    gl_lds16(kg1, &Ks[bufI][wave * 16 + 8][0]);               \
    kg0 += (size_t)64 * Dc; kg1 += (size_t)64 * Dc;           \
  }
#define STAGE_V(bufI)                                         \
  {                                                           \
    gl_lds16(vg0, &Vts[bufI][wave * 16][0]);                  \
    gl_lds16(vg1, &Vts[bufI][wave * 16 + 8][0]);              \
    vg0 += 64; vg1 += 64;                                     \
  }
  bfrag qf[2][2];
  for (int mi = 0; mi < 2; ++mi)
    for (int ks = 0; ks < 2; ++ks)
      qf[mi][ks] = *(const bfrag*)(Q + (size_t)(b * Sc + q0 + wq + mi * 16 + lr) * Dc +
                                   h * DHc + ks * 32 + lq * 8);
  f32x4 oacc[2][4] = {};  // O^T
  f32x4 oext[2] = {};     // row-sum accumulator (every reg = rsum(q=lr))
  const f32x4 zero4 = {0.0f, 0.0f, 0.0f, 0.0f};
  FB ones;
  ones.w[0] = 0x3F803F80u; ones.w[1] = 0x3F803F80u; ones.w[2] = 0x3F803F80u; ones.w[3] = 0x3F803F80u;
  const int lrx = lr & 7;
  const int NT = Sc / 64;
  f32x4 saccA[2][4], saccB[2][4];

// S^T for Kbuf[KB] into DST; C-in = zero quad (mask baked into K).
#define SBLOCK(KB, DST)                                                                       \
  {                                                                                           \
    for (int nk = 0; nk < 4; ++nk) {                                                          \
      const int kr = nk * 16 + lr;                                                            \
      bfrag kf0 = *(const bfrag*)(&Ks[KB][kr][(lq ^ lrx) * 8]);                               \
      bfrag kf1 = *(const bfrag*)(&Ks[KB][kr][((4 + lq) ^ lrx) * 8]);                         \
      for (int mi = 0; mi < 2; ++mi) {                                                        \
        f32x4 t = __builtin_amdgcn_mfma_f32_16x16x32_bf16(kf0, qf[mi][0], zero4, 0, 0, 0);    \
        DST[mi][nk] = __builtin_amdgcn_mfma_f32_16x16x32_bf16(kf1, qf[mi][1], t, 0, 0, 0);    \
      }                                                                                       \
    }                                                                                         \
  }

// softmax + PV + rowsum for tile in SRC, V from Vbuf[VB].
#define PVBLOCK(VB, SRC)                                                                      \
  {                                                                                           \
    for (int c = 0; c < 2; ++c) {                                                             \
      FB pb[2];                                                                               \
      for (int mi = 0; mi < 2; ++mi) {                                                        \
        const f32x4 s0 = SRC[mi][2 * c];                                                      \
        const f32x4 s1 = SRC[mi][2 * c + 1];                                                  \
        u32 w0 = pkbf(EXP2(s0[0]), EXP2(s0[1]));                                              \
        u32 w1 = pkbf(EXP2(s0[2]), EXP2(s0[3]));                                              \
        u32 w2 = pkbf(EXP2(s1[0]), EXP2(s1[1]));                                              \
        u32 w3 = pkbf(EXP2(s1[2]), EXP2(s1[3]));                                              \
        pl32swap(w0, w2); pl16swap(w0, w2);                                                   \
        pl32swap(w1, w3); pl16swap(w1, w3);                                                   \
        pb[mi].w[0] = w0; pb[mi].w[1] = w1; pb[mi].w[2] = w2; pb[mi].w[3] = w3;               \
      }                                                                                       \
      for (int nd = 0; nd < 4; ++nd) {                                                        \
        const int dr = nd * 16 + lr;                                                          \
        const bfrag vb = *(const bfrag*)(&Vts[VB][dr][((4 * c + lq) ^ lrx) * 8]);             \
        oacc[0][nd] = __builtin_amdgcn_mfma_f32_16x16x32_bf16(vb, pb[0].f, oacc[0][nd], 0, 0, 0); \
        oacc[1][nd] = __builtin_amdgcn_mfma_f32_16x16x32_bf16(vb, pb[1].f, oacc[1][nd], 0, 0, 0); \
      }                                                                                       \
      oext[0] = __builtin_amdgcn_mfma_f32_16x16x32_bf16(ones.f, pb[0].f, oext[0], 0, 0, 0);   \
      oext[1] = __builtin_amdgcn_mfma_f32_16x16x32_bf16(ones.f, pb[1].f, oext[1], 0, 0, 0);   \
    }                                                                                         \
  }

  // ---- prologue: init nm; stage K0,V0; count masked keys of batch b; barrier ----
  if (tid == 0) nmS = 0;
  __syncthreads();
  STAGE_K(0);
  STAGE_V(0);
  {
    int cnt = 0;
    const float4* mrow = (const float4*)(maskf + b * Sc);
    for (int i = tid; i < Sc / 4; i += 256) {
      float4 m4 = mrow[i];
      cnt += (m4.x != 0.0f) + (m4.y != 0.0f) + (m4.z != 0.0f) + (m4.w != 0.0f);
    }
    if (cnt) atomicAdd(&nmS, cnt);
  }
  __syncthreads();
  const float nmf = (float)nmS;
  STAGE_K(1);
  SBLOCK(0, saccA);

  for (int kt = 0; kt < NT; kt += 2) {
    // ---- even body: S(kt) in saccA ----
    __syncthreads();                 // drains K(kt+1), V(kt); all waves done with Kbuf0, Vbuf1
    if (kt + 2 < NT) STAGE_K(0);     // K(kt+2)
    STAGE_V(1);                      // V(kt+1)  (kt+1 <= NT-1 always here)
    SBLOCK(1, saccB);                // S(kt+1) MFMAs issued before softmax(kt)
    PVBLOCK(0, saccA);               // softmax+PV(kt) overlaps S(kt+1)
    // ---- odd body: S(kt+1) in saccB ----
    __syncthreads();                 // drains K(kt+2), V(kt+1)
    if (kt + 3 < NT) STAGE_K(1);     // K(kt+3)
    if (kt + 2 < NT) {
      STAGE_V(0);                    // V(kt+2)
      SBLOCK(0, saccA);              // S(kt+2)
    }
    PVBLOCK(1, saccB);               // softmax+PV(kt+1)
  }

  for (int mi = 0; mi < 2; ++mi) {
    float inv = 1.0f / (oext[mi][0] - nmf);   // remove masked keys' p=1 contributions
    u16* rowp = Aout + (size_t)(b * Sc + q0 + wq + mi * 16 + lr) * Dc + h * DHc;
    for (int nd = 0; nd < 4; ++nd) {
      float o0 = oacc[mi][nd][0] * inv, o1 = oacc[mi][nd][1] * inv;
      float o2 = oacc[mi][nd][2] * inv, o3 = oacc[mi][nd][3] * inv;
      uint2 st;
      st.x = pkbf(o0, o1);
      st.y = pkbf(o2, o3);
      *(uint2*)(rowp + nd * 16 + lq * 4) = st;
    }
  }
#undef STAGE_K
#undef STAGE_V
#undef SBLOCK
#undef PVBLOCK
}

extern "C" void kernel_launch(void* const* d_in, const int* in_sizes, int n_in,
                              void* d_out, int out_size, void* d_ws, size_t ws_size,
                              hipStream_t stream) {
  (void)in_sizes; (void)n_in; (void)out_size;
  char* ws = (char*)d_ws;
  int* flags = (int*)ws;                              // 256 B
  float* maskf = (float*)(ws + 256);                  // 32 KB
  float* biasf = (float*)(ws + 256 + Bc * Sc * 4);    // 16 KB
  u16* WqT = (u16*)(ws + 65536);
  u16* WkT = WqT + (size_t)Dc * Dc;
  u16* WvT = WkT + (size_t)Dc * Dc;
  u16* WoT = WvT + (size_t)Dc * Dc;
  u16* Qb  = WoT + (size_t)Dc * Dc;
  u16* Kb  = Qb + (size_t)Bc * Sc * Dc;
  u16* Vb  = Kb + (size_t)Bc * Sc * Dc;               // unused (V^T written directly)
  u16* Vtb = Vb + (size_t)Bc * Sc * Dc;
  u16* Ab  = Vtb + (size_t)Bc * Sc * Dc;
  u16* qbf = Ab + (size_t)Bc * Sc * Dc;               // bf16 copies of inputs (contiguous q,k,v)
  u16* kbf = qbf + (size_t)Bc * Sc * Dc;
  u16* vbf = kbf + (size_t)Bc * Sc * Dc;
  const size_t need = (size_t)((char*)(vbf + (size_t)Bc * Sc * Dc) - ws);
  const bool have_cvt = ws_size >= need;
  const int cvtBlocks = have_cvt ? 3 * 4096 : 0;

  prep_flags_k<<<1, 256, 0, stream>>>(d_in[0], d_in[3], flags);
  aux_all<<<48 + cvtBlocks + 1024, 256, 0, stream>>>(
      d_in[4], d_in[6], d_in[8], d_in[10], WqT, WkT, WvT, WoT,
      d_in[0], d_in[1], d_in[2], qbf, kbf, vbf,
      d_in[3], d_in[5], d_in[7], d_in[9], d_in[11],
      flags, maskf, biasf, cvtBlocks);
  const int nblk = (Bc * Sc / BM) * (Dc / BN);        // 512
  if (have_cvt) {
    // z-fused QKV: z=0 -> Qb, z=1 -> Kb (masked rows), z=2 -> V^T (masked cols)
    gemm_bt<<<dim3(nblk, 1, 3), 256, 0, stream>>>(qbf, WqT, biasf, Qb, Vtb, maskf, flags,
                                                  Bc * Sc, Dc, Dc, 1, 0, 1, 0);
  } else {
    gemm_bt<<<nblk, 256, 0, stream>>>(d_in[0], WqT, biasf, Qb, nullptr, maskf, flags,
                                      Bc * Sc, Dc, Dc, 0, 0, 0, 0);
    gemm_bt<<<nblk, 256, 0, stream>>>(d_in[1], WkT, biasf + Dc, Kb, nullptr, maskf, flags,
                                      Bc * Sc, Dc, Dc, 0, 0, 0, 1);
    gemm_bt<<<nblk, 256, 0, stream>>>(d_in[2], WvT, biasf + 2 * Dc, Vtb, nullptr, maskf, flags,
                                      Bc * Sc, Dc, Dc, 0, 2, 0, 1);
  }
  attn_kernel<<<dim3(64, 16), 256, 0, stream>>>(Qb, Kb, Vtb, maskf, Ab);
  gemm_bt<<<nblk, 256, 0, stream>>>(Ab, WoT, biasf + 3 * Dc, d_out, nullptr, maskf, flags,
                                    Bc * Sc, Dc, Dc, 1, 1, 0, 0);
}